// Round 1
// baseline (12275.142 us; speedup 1.0000x reference)
//
#include <hip/hip_runtime.h>

#define NUM_USERS 100000
#define NUM_ITEMS 50000
#define NN (NUM_USERS + NUM_ITEMS)
#define EMB_DIM 64
#define BATCH 16384

// init: emb = acc = concat(user_emb, item_emb), as float4 lanes
__global__ void lgcn_init(const float4* __restrict__ user_emb,
                          const float4* __restrict__ item_emb,
                          float4* __restrict__ emb, float4* __restrict__ acc,
                          int n_user4, int n_tot4) {
    int i = blockIdx.x * blockDim.x + threadIdx.x;
    if (i >= n_tot4) return;
    float4 v = (i < n_user4) ? user_emb[i] : item_emb[i - n_user4];
    emb[i] = v;
    acc[i] = v;
}

// SpMM scatter: 16 threads per edge, 1 float4 (4 dims) per thread
__global__ void lgcn_scatter(const int* __restrict__ rows,
                             const int* __restrict__ cols,
                             const float* __restrict__ vals,
                             const float4* __restrict__ emb,
                             float* __restrict__ nxt, int nnz) {
    long long t = (long long)blockIdx.x * blockDim.x + threadIdx.x;
    int e = (int)(t >> 4);
    if (e >= nnz) return;
    int l = (int)(t & 15);
    int r = rows[e];
    int c = cols[e];
    float v = vals[e];
    float4 src = emb[(long long)c * 16 + l];   // coalesced 256B per edge-group
    float* dst = nxt + (long long)r * EMB_DIM + l * 4;
    atomicAdd(dst + 0, v * src.x);
    atomicAdd(dst + 1, v * src.y);
    atomicAdd(dst + 2, v * src.z);
    atomicAdd(dst + 3, v * src.w);
}

// acc += nxt
__global__ void lgcn_add(float4* __restrict__ acc, const float4* __restrict__ nxt,
                         int n_tot4) {
    int i = blockIdx.x * blockDim.x + threadIdx.x;
    if (i >= n_tot4) return;
    float4 a = acc[i], b = nxt[i];
    a.x += b.x; a.y += b.y; a.z += b.z; a.w += b.w;
    acc[i] = a;
}

// out[b] = dot(acc[u], acc[NUM_USERS+i]) / 16 ; 16 lanes per output
__global__ void lgcn_dot(const float* __restrict__ acc,
                         const int* __restrict__ user_idx,
                         const int* __restrict__ item_idx,
                         float* __restrict__ out, int batch) {
    int t = blockIdx.x * blockDim.x + threadIdx.x;
    int b = t >> 4;
    if (b >= batch) return;
    int l = t & 15;
    int u = user_idx[b];
    int it = item_idx[b];
    const float4* ue = (const float4*)(acc + (long long)u * EMB_DIM);
    const float4* ie = (const float4*)(acc + (long long)(NUM_USERS + it) * EMB_DIM);
    float4 a = ue[l], c = ie[l];
    float s = a.x * c.x + a.y * c.y + a.z * c.z + a.w * c.w;
    s += __shfl_down(s, 8, 16);
    s += __shfl_down(s, 4, 16);
    s += __shfl_down(s, 2, 16);
    s += __shfl_down(s, 1, 16);
    if (l == 0) out[b] = s * (1.0f / 16.0f);
}

extern "C" void kernel_launch(void* const* d_in, const int* in_sizes, int n_in,
                              void* d_out, int out_size, void* d_ws, size_t ws_size,
                              hipStream_t stream) {
    const float* user_emb = (const float*)d_in[0];
    const float* item_emb = (const float*)d_in[1];
    const int*   rows     = (const int*)d_in[2];
    const int*   cols     = (const int*)d_in[3];
    const float* vals     = (const float*)d_in[4];
    const int*   user_idx = (const int*)d_in[5];
    const int*   item_idx = (const int*)d_in[6];
    // d_in[7] = n_layers (device scalar) — fixed at 3 per problem spec
    float* out = (float*)d_out;

    const int nnz = in_sizes[2];
    const size_t node_floats = (size_t)NN * EMB_DIM;   // 9.6M floats

    float* emb = (float*)d_ws;
    float* nxt = emb + node_floats;
    float* acc = nxt + node_floats;

    const int n_tot4  = NN * EMB_DIM / 4;              // 2.4M float4
    const int n_user4 = NUM_USERS * EMB_DIM / 4;

    lgcn_init<<<(n_tot4 + 255) / 256, 256, 0, stream>>>(
        (const float4*)user_emb, (const float4*)item_emb,
        (float4*)emb, (float4*)acc, n_user4, n_tot4);

    for (int layer = 0; layer < 3; ++layer) {
        hipMemsetAsync(nxt, 0, node_floats * sizeof(float), stream);
        long long threads = (long long)nnz * 16;
        int grid = (int)((threads + 255) / 256);
        lgcn_scatter<<<grid, 256, 0, stream>>>(rows, cols, vals,
                                               (const float4*)emb, nxt, nnz);
        lgcn_add<<<(n_tot4 + 255) / 256, 256, 0, stream>>>(
            (float4*)acc, (const float4*)nxt, n_tot4);
        float* tmp = emb; emb = nxt; nxt = tmp;
    }

    lgcn_dot<<<(BATCH * 16 + 255) / 256, 256, 0, stream>>>(
        acc, user_idx, item_idx, out, BATCH);
}

// Round 2
// 1441.843 us; speedup vs baseline: 8.5135x; 8.5135x over previous
//
#include <hip/hip_runtime.h>

#define NUM_USERS 100000
#define NUM_ITEMS 50000
#define NN (NUM_USERS + NUM_ITEMS)
#define EMB_DIM 64
#define BATCH 16384
#define SCAN_CHUNK 2048   // elements per scan1 block (256 thr x 8)

// init: emb = acc = concat(user_emb, item_emb)
__global__ void lgcn_init(const float4* __restrict__ user_emb,
                          const float4* __restrict__ item_emb,
                          float4* __restrict__ emb, float4* __restrict__ acc,
                          int n_user4, int n_tot4) {
    int i = blockIdx.x * blockDim.x + threadIdx.x;
    if (i >= n_tot4) return;
    float4 v = (i < n_user4) ? user_emb[i] : item_emb[i - n_user4];
    emb[i] = v;
    acc[i] = v;
}

// ---- CSR build ----
__global__ void lgcn_hist(const int* __restrict__ rows, int* __restrict__ deg, int nnz) {
    int e = blockIdx.x * blockDim.x + threadIdx.x;
    if (e >= nnz) return;
    atomicAdd(&deg[rows[e]], 1);
}

// per-block exclusive scan (2048 elems/block), emits block totals
__global__ void lgcn_scan1(const int* __restrict__ in, int* __restrict__ out,
                           int* __restrict__ blockSums, int n) {
    __shared__ int lds[256];
    int t = threadIdx.x;
    int base = blockIdx.x * SCAN_CHUNK + t * 8;
    int v[8]; int s = 0;
#pragma unroll
    for (int k = 0; k < 8; ++k) {
        int idx = base + k;
        v[k] = (idx < n) ? in[idx] : 0;
        s += v[k];
    }
    lds[t] = s;
    __syncthreads();
    for (int off = 1; off < 256; off <<= 1) {
        int x = (t >= off) ? lds[t - off] : 0;
        __syncthreads();
        lds[t] += x;
        __syncthreads();
    }
    int run = (t == 0) ? 0 : lds[t - 1];
    if (t == 255) blockSums[blockIdx.x] = lds[255];
#pragma unroll
    for (int k = 0; k < 8; ++k) {
        int idx = base + k;
        if (idx < n) out[idx] = run;
        run += v[k];
    }
}

// exclusive scan of block sums (nb <= 2048), single block
__global__ void lgcn_scan2(int* __restrict__ blockSums, int nb) {
    __shared__ int lds[2048];
    int t = threadIdx.x;
    for (int i = t; i < nb; i += 256) lds[i] = blockSums[i];
    __syncthreads();
    if (t == 0) {
        int run = 0;
        for (int i = 0; i < nb; ++i) { int x = lds[i]; lds[i] = run; run += x; }
    }
    __syncthreads();
    for (int i = t; i < nb; i += 256) blockSums[i] = lds[i];
}

// add block offsets; also seed cursor and write row_ptr[n] = nnz
__global__ void lgcn_scan3(int* __restrict__ row_ptr, const int* __restrict__ blockSums,
                           int* __restrict__ cursor, int n, int nnz) {
    int i = blockIdx.x * blockDim.x + threadIdx.x;
    if (i == 0) row_ptr[n] = nnz;
    if (i >= n) return;
    int v = row_ptr[i] + blockSums[i / SCAN_CHUNK];
    row_ptr[i] = v;
    cursor[i] = v;
}

__global__ void lgcn_fill(const int* __restrict__ rows, const int* __restrict__ cols,
                          const float* __restrict__ vals, int* __restrict__ cursor,
                          int* __restrict__ col_s, float* __restrict__ val_s, int nnz) {
    int e = blockIdx.x * blockDim.x + threadIdx.x;
    if (e >= nnz) return;
    int r = rows[e];
    int p = atomicAdd(&cursor[r], 1);
    col_s[p] = cols[e];
    val_s[p] = vals[e];
}

// ---- gather SpMM: one wave (64 lanes) per row; lane l owns dim l.
// nxt[r] = sum_e val*emb[col]; acc[r] += nxt[r]  (fused)
__global__ void lgcn_spmm(const int* __restrict__ row_ptr,
                          const int* __restrict__ col_s,
                          const float* __restrict__ val_s,
                          const float* __restrict__ emb,
                          float* __restrict__ nxt,
                          float* __restrict__ acc) {
    int wid = (blockIdx.x * blockDim.x + threadIdx.x) >> 6;
    int lane = threadIdx.x & 63;
    if (wid >= NN) return;
    int start = row_ptr[wid];
    int end   = row_ptr[wid + 1];
    float a = 0.0f;
    for (int e0 = start; e0 < end; e0 += 64) {
        int n = end - e0;
        if (n > 64) n = 64;
        int c = 0; float v = 0.0f;
        if (lane < n) { c = col_s[e0 + lane]; v = val_s[e0 + lane]; }
        for (int j = 0; j < n; ++j) {
            int cc = __shfl(c, j);
            float vv = __shfl(v, j);
            a += vv * emb[(long long)cc * EMB_DIM + lane];
        }
    }
    long long o = (long long)wid * EMB_DIM + lane;
    nxt[o] = a;
    acc[o] += a;
}

// out[b] = dot(acc[u], acc[NUM_USERS+i]) / 16 ; 16 lanes per output
__global__ void lgcn_dot(const float* __restrict__ acc,
                         const int* __restrict__ user_idx,
                         const int* __restrict__ item_idx,
                         float* __restrict__ out, int batch) {
    int t = blockIdx.x * blockDim.x + threadIdx.x;
    int b = t >> 4;
    if (b >= batch) return;
    int l = t & 15;
    int u = user_idx[b];
    int it = item_idx[b];
    const float4* ue = (const float4*)(acc + (long long)u * EMB_DIM);
    const float4* ie = (const float4*)(acc + (long long)(NUM_USERS + it) * EMB_DIM);
    float4 a = ue[l], c = ie[l];
    float s = a.x * c.x + a.y * c.y + a.z * c.z + a.w * c.w;
    s += __shfl_down(s, 8, 16);
    s += __shfl_down(s, 4, 16);
    s += __shfl_down(s, 2, 16);
    s += __shfl_down(s, 1, 16);
    if (l == 0) out[b] = s * (1.0f / 16.0f);
}

extern "C" void kernel_launch(void* const* d_in, const int* in_sizes, int n_in,
                              void* d_out, int out_size, void* d_ws, size_t ws_size,
                              hipStream_t stream) {
    const float* user_emb = (const float*)d_in[0];
    const float* item_emb = (const float*)d_in[1];
    const int*   rows     = (const int*)d_in[2];
    const int*   cols     = (const int*)d_in[3];
    const float* vals     = (const float*)d_in[4];
    const int*   user_idx = (const int*)d_in[5];
    const int*   item_idx = (const int*)d_in[6];
    float* out = (float*)d_out;

    const int nnz = in_sizes[2];
    const size_t node_floats = (size_t)NN * EMB_DIM;   // 9.6M

    // workspace layout
    float* emb     = (float*)d_ws;
    float* nxt     = emb + node_floats;
    float* acc     = nxt + node_floats;
    int*   col_s   = (int*)(acc + node_floats);
    float* val_s   = (float*)(col_s + nnz);
    int*   deg     = (int*)(val_s + nnz);
    int*   row_ptr = deg + NN;            // NN+1 entries
    int*   cursor  = row_ptr + NN + 1;
    int*   bsums   = cursor + NN;

    const int n_tot4  = NN * EMB_DIM / 4;
    const int n_user4 = NUM_USERS * EMB_DIM / 4;

    lgcn_init<<<(n_tot4 + 255) / 256, 256, 0, stream>>>(
        (const float4*)user_emb, (const float4*)item_emb,
        (float4*)emb, (float4*)acc, n_user4, n_tot4);

    // CSR build
    hipMemsetAsync(deg, 0, NN * sizeof(int), stream);
    lgcn_hist<<<(nnz + 255) / 256, 256, 0, stream>>>(rows, deg, nnz);
    const int nScanBlocks = (NN + SCAN_CHUNK - 1) / SCAN_CHUNK;   // 74
    lgcn_scan1<<<nScanBlocks, 256, 0, stream>>>(deg, row_ptr, bsums, NN);
    lgcn_scan2<<<1, 256, 0, stream>>>(bsums, nScanBlocks);
    lgcn_scan3<<<(NN + 255) / 256, 256, 0, stream>>>(row_ptr, bsums, cursor, NN, nnz);
    lgcn_fill<<<(nnz + 255) / 256, 256, 0, stream>>>(rows, cols, vals, cursor,
                                                     col_s, val_s, nnz);

    // 3 layers of gather SpMM (ping-pong emb/nxt), acc fused
    const int spmm_blocks = (NN * 64 + 255) / 256;   // one wave per row
    for (int layer = 0; layer < 3; ++layer) {
        lgcn_spmm<<<spmm_blocks, 256, 0, stream>>>(row_ptr, col_s, val_s,
                                                   emb, nxt, acc);
        float* tmp = emb; emb = nxt; nxt = tmp;
    }

    lgcn_dot<<<(BATCH * 16 + 255) / 256, 256, 0, stream>>>(
        acc, user_idx, item_idx, out, BATCH);
}

// Round 3
// 1204.761 us; speedup vs baseline: 10.1889x; 1.1968x over previous
//
#include <hip/hip_runtime.h>

#define NUM_USERS 100000
#define NUM_ITEMS 50000
#define NN (NUM_USERS + NUM_ITEMS)
#define EMB_DIM 64
#define BATCH 16384
#define SCAN_CHUNK 2048   // elements per scan1 block (256 thr x 8)

// init: emb = acc = concat(user_emb, item_emb)
__global__ void lgcn_init(const float4* __restrict__ user_emb,
                          const float4* __restrict__ item_emb,
                          float4* __restrict__ emb, float4* __restrict__ acc,
                          int n_user4, int n_tot4) {
    int i = blockIdx.x * blockDim.x + threadIdx.x;
    if (i >= n_tot4) return;
    float4 v = (i < n_user4) ? user_emb[i] : item_emb[i - n_user4];
    emb[i] = v;
    acc[i] = v;
}

// ---- CSR build ----
__global__ void lgcn_hist(const int* __restrict__ rows, int* __restrict__ deg, int nnz) {
    int e = blockIdx.x * blockDim.x + threadIdx.x;
    if (e >= nnz) return;
    atomicAdd(&deg[rows[e]], 1);
}

// per-block exclusive scan (2048 elems/block), emits block totals
__global__ void lgcn_scan1(const int* __restrict__ in, int* __restrict__ out,
                           int* __restrict__ blockSums, int n) {
    __shared__ int lds[256];
    int t = threadIdx.x;
    int base = blockIdx.x * SCAN_CHUNK + t * 8;
    int v[8]; int s = 0;
#pragma unroll
    for (int k = 0; k < 8; ++k) {
        int idx = base + k;
        v[k] = (idx < n) ? in[idx] : 0;
        s += v[k];
    }
    lds[t] = s;
    __syncthreads();
    for (int off = 1; off < 256; off <<= 1) {
        int x = (t >= off) ? lds[t - off] : 0;
        __syncthreads();
        lds[t] += x;
        __syncthreads();
    }
    int run = (t == 0) ? 0 : lds[t - 1];
    if (t == 255) blockSums[blockIdx.x] = lds[255];
#pragma unroll
    for (int k = 0; k < 8; ++k) {
        int idx = base + k;
        if (idx < n) out[idx] = run;
        run += v[k];
    }
}

// exclusive scan of block sums (nb small), single block
__global__ void lgcn_scan2(int* __restrict__ blockSums, int nb) {
    __shared__ int lds[2048];
    int t = threadIdx.x;
    for (int i = t; i < nb; i += 256) lds[i] = blockSums[i];
    __syncthreads();
    if (t == 0) {
        int run = 0;
        for (int i = 0; i < nb; ++i) { int x = lds[i]; lds[i] = run; run += x; }
    }
    __syncthreads();
    for (int i = t; i < nb; i += 256) blockSums[i] = lds[i];
}

// add block offsets; also seed cursor and write row_ptr[n] = nnz
__global__ void lgcn_scan3(int* __restrict__ row_ptr, const int* __restrict__ blockSums,
                           int* __restrict__ cursor, int n, int nnz) {
    int i = blockIdx.x * blockDim.x + threadIdx.x;
    if (i == 0) row_ptr[n] = nnz;
    if (i >= n) return;
    int v = row_ptr[i] + blockSums[i / SCAN_CHUNK];
    row_ptr[i] = v;
    cursor[i] = v;
}

// fill CSR with packed {col, val_bits} — one 8B random store per edge
__global__ void lgcn_fill(const int* __restrict__ rows, const int* __restrict__ cols,
                          const float* __restrict__ vals, int* __restrict__ cursor,
                          int2* __restrict__ cv, int nnz) {
    int e = blockIdx.x * blockDim.x + threadIdx.x;
    if (e >= nnz) return;
    int r = rows[e];
    int p = atomicAdd(&cursor[r], 1);
    cv[p] = make_int2(cols[e], __float_as_int(vals[e]));
}

// ---- gather SpMM: one wave per row; 4 edge-groups x 16 dim-lanes.
// Group g (lanes 16g..16g+15) processes edges start+j+g; lane owns float4 slice.
// nxt[r] = sum_e val*emb[col]; acc[r] += nxt[r]  (fused)
__global__ void lgcn_spmm(const int* __restrict__ row_ptr,
                          const int2* __restrict__ cv,
                          const float4* __restrict__ emb4,
                          float4* __restrict__ nxt4,
                          float4* __restrict__ acc4) {
    int wid = (blockIdx.x * blockDim.x + threadIdx.x) >> 6;
    int lane = threadIdx.x & 63;
    if (wid >= NN) return;
    int start = row_ptr[wid];
    int end   = row_ptr[wid + 1];
    int grp  = lane >> 4;    // 0..3
    int dim4 = lane & 15;    // float4 index within row
    float4 a = {0.f, 0.f, 0.f, 0.f};
    for (int e0 = start; e0 < end; e0 += 64) {
        int n = end - e0;
        if (n > 64) n = 64;
        int c = 0; float v = 0.0f;
        if (lane < n) {
            int2 p = cv[e0 + lane];
            c = p.x; v = __int_as_float(p.y);
        }
        for (int j = 0; j < n; j += 4) {
            int idx = j + grp;
            int cc   = __shfl(c, idx);
            float vv = __shfl(v, idx);
            if (idx < n) {
                float4 s = emb4[(long long)cc * 16 + dim4];
                a.x += vv * s.x; a.y += vv * s.y; a.z += vv * s.z; a.w += vv * s.w;
            }
        }
    }
    // reduce the 4 edge-groups onto group 0
    a.x += __shfl_xor(a.x, 16); a.y += __shfl_xor(a.y, 16);
    a.z += __shfl_xor(a.z, 16); a.w += __shfl_xor(a.w, 16);
    a.x += __shfl_xor(a.x, 32); a.y += __shfl_xor(a.y, 32);
    a.z += __shfl_xor(a.z, 32); a.w += __shfl_xor(a.w, 32);
    if (grp == 0) {
        long long o = (long long)wid * 16 + dim4;
        float4 av = acc4[o];
        nxt4[o] = a;
        av.x += a.x; av.y += a.y; av.z += a.z; av.w += a.w;
        acc4[o] = av;
    }
}

// out[b] = dot(acc[u], acc[NUM_USERS+i]) / 16 ; 16 lanes per output
__global__ void lgcn_dot(const float* __restrict__ acc,
                         const int* __restrict__ user_idx,
                         const int* __restrict__ item_idx,
                         float* __restrict__ out, int batch) {
    int t = blockIdx.x * blockDim.x + threadIdx.x;
    int b = t >> 4;
    if (b >= batch) return;
    int l = t & 15;
    int u = user_idx[b];
    int it = item_idx[b];
    const float4* ue = (const float4*)(acc + (long long)u * EMB_DIM);
    const float4* ie = (const float4*)(acc + (long long)(NUM_USERS + it) * EMB_DIM);
    float4 a = ue[l], c = ie[l];
    float s = a.x * c.x + a.y * c.y + a.z * c.z + a.w * c.w;
    s += __shfl_down(s, 8, 16);
    s += __shfl_down(s, 4, 16);
    s += __shfl_down(s, 2, 16);
    s += __shfl_down(s, 1, 16);
    if (l == 0) out[b] = s * (1.0f / 16.0f);
}

extern "C" void kernel_launch(void* const* d_in, const int* in_sizes, int n_in,
                              void* d_out, int out_size, void* d_ws, size_t ws_size,
                              hipStream_t stream) {
    const float* user_emb = (const float*)d_in[0];
    const float* item_emb = (const float*)d_in[1];
    const int*   rows     = (const int*)d_in[2];
    const int*   cols     = (const int*)d_in[3];
    const float* vals     = (const float*)d_in[4];
    const int*   user_idx = (const int*)d_in[5];
    const int*   item_idx = (const int*)d_in[6];
    float* out = (float*)d_out;

    const int nnz = in_sizes[2];
    const size_t node_floats = (size_t)NN * EMB_DIM;   // 9.6M

    // workspace layout
    float* emb     = (float*)d_ws;
    float* nxt     = emb + node_floats;
    float* acc     = nxt + node_floats;
    int2*  cv      = (int2*)(acc + node_floats);       // nnz entries (8B each)
    int*   deg     = (int*)(cv + nnz);
    int*   row_ptr = deg + NN;                         // NN+1 entries
    int*   cursor  = row_ptr + NN + 1;
    int*   bsums   = cursor + NN;

    const int n_tot4  = NN * EMB_DIM / 4;
    const int n_user4 = NUM_USERS * EMB_DIM / 4;

    lgcn_init<<<(n_tot4 + 255) / 256, 256, 0, stream>>>(
        (const float4*)user_emb, (const float4*)item_emb,
        (float4*)emb, (float4*)acc, n_user4, n_tot4);

    // CSR build
    hipMemsetAsync(deg, 0, NN * sizeof(int), stream);
    lgcn_hist<<<(nnz + 255) / 256, 256, 0, stream>>>(rows, deg, nnz);
    const int nScanBlocks = (NN + SCAN_CHUNK - 1) / SCAN_CHUNK;   // 74
    lgcn_scan1<<<nScanBlocks, 256, 0, stream>>>(deg, row_ptr, bsums, NN);
    lgcn_scan2<<<1, 256, 0, stream>>>(bsums, nScanBlocks);
    lgcn_scan3<<<(NN + 255) / 256, 256, 0, stream>>>(row_ptr, bsums, cursor, NN, nnz);
    lgcn_fill<<<(nnz + 255) / 256, 256, 0, stream>>>(rows, cols, vals, cursor, cv, nnz);

    // 3 layers of gather SpMM (ping-pong emb/nxt), acc fused
    const int spmm_blocks = (NN * 64 + 255) / 256;   // one wave per row
    for (int layer = 0; layer < 3; ++layer) {
        lgcn_spmm<<<spmm_blocks, 256, 0, stream>>>(row_ptr, cv,
                                                   (const float4*)emb,
                                                   (float4*)nxt, (float4*)acc);
        float* tmp = emb; emb = nxt; nxt = tmp;
    }

    lgcn_dot<<<(BATCH * 16 + 255) / 256, 256, 0, stream>>>(
        acc, user_idx, item_idx, out, BATCH);
}